// Round 7
// baseline (24.518 us; speedup 1.0000x reference)
//
#include <hip/hip_runtime.h>
#include <hip/hip_bf16.h>

#define NQ 6
#define DIM 64
#define NLAYERS 6

typedef __attribute__((ext_vector_type(8))) short bf16x8;
typedef __attribute__((ext_vector_type(4))) float f32x4;

// ---------------------------------------------------------------------------
// build_M: fused circuit matrix M = P*U5*...*P*U0*F (complex 64x64), emitted
// as MFMA fragments (bf16 hi/lo split), frag-linear:
//   frag f = (jt*2 + chunk)*4 + plane  (0=r_hi 1=r_lo 2=i_hi 3=i_lo)
//   ushort addr = f*512 + lane16*8 + e
//   lane16 = (j&15) + 16*((k>>3)&3), chunk = k>>5, e = k&7, jt = j>>4.
// Role-agnostic packing: both operands use the same (lanegrp,e)->k bijection,
// so the positional A/B pairing is consistent (validated R4 & R6 both pass).
// ---------------------------------------------------------------------------
__global__ __launch_bounds__(64) void build_M(const float* __restrict__ w,
                                              unsigned short* __restrict__ Bf) {
    const int k = blockIdx.x;    // column 0..63
    const int j = threadIdx.x;   // row/lane 0..63

    int t = (j * k) & 63;
    float sv, cv;
    sincospif((float)t / 32.0f, &sv, &cv);   // exp(i*pi*t/32)
    float vr = cv * 0.125f;
    float vi = sv * 0.125f;

    int m = j;
#pragma unroll
    for (int q = 0; q < NQ; ++q) {
        int cb = 5 - q;
        int tb = 5 - ((q + 1) % NQ);
        if ((m >> cb) & 1) m ^= (1 << tb);
    }
    const int dst4 = m << 2;

    for (int l = 0; l < NLAYERS; ++l) {
#pragma unroll
        for (int q = 0; q < NQ; ++q) {
            float th = w[l * NQ + q] * 0.5f;
            float c = cosf(th), s = sinf(th);
            int b = 5 - q;
            float pr = __shfl_xor(vr, 1 << b);
            float pi = __shfl_xor(vi, 1 << b);
            float sgn = ((j >> b) & 1) ? s : -s;
            vr = c * vr + sgn * pr;
            vi = c * vi + sgn * pi;
        }
        vr = __int_as_float(__builtin_amdgcn_ds_permute(dst4, __float_as_int(vr)));
        vi = __int_as_float(__builtin_amdgcn_ds_permute(dst4, __float_as_int(vi)));
    }

    const int jt = j >> 4;
    const int lane16 = (j & 15) + 16 * ((k >> 3) & 3);
    const int chunk = k >> 5;
    const int e = k & 7;
    const int base = ((jt * 2 + chunk) * 4) * 512 + lane16 * 8 + e;

    __hip_bfloat16 rh = __float2bfloat16(vr);
    __hip_bfloat16 rl = __float2bfloat16(vr - __bfloat162float(rh));
    __hip_bfloat16 ih = __float2bfloat16(vi);
    __hip_bfloat16 il = __float2bfloat16(vi - __bfloat162float(ih));
    Bf[base]        = *(unsigned short*)&rh;
    Bf[base + 512]  = *(unsigned short*)&rl;
    Bf[base + 1024] = *(unsigned short*)&ih;
    Bf[base + 1536] = *(unsigned short*)&il;
}

__device__ __forceinline__ void split8(const float* f, bf16x8& h, bf16x8& l) {
#pragma unroll
    for (int i = 0; i < 8; ++i) {
        __hip_bfloat16 hh = __float2bfloat16(f[i]);
        __hip_bfloat16 ll = __float2bfloat16(f[i] - __bfloat162float(hh));
        h[i] = *(short*)&hh;
        l[i] = *(short*)&ll;
    }
}

// ---------------------------------------------------------------------------
// qenc_main: NO LDS, NO barrier. Each wave owns one 16-row tile (16 waves/CU
// at 1024 blocks). M is the A-operand, streamed from global per jt/c group
// (each lane its own 16B; 32KB image stays L1-resident per CU). x is the
// B-operand in regs. Epilogue: lane (r,g) holds out[row0+r][jt*16+4g..+3],
// inv lane-resident -> 4 coalesced float4 stores.
// ---------------------------------------------------------------------------
__global__ __launch_bounds__(256) void qenc_main(const float* __restrict__ x,
                                                 const unsigned short* __restrict__ Bf,
                                                 float* __restrict__ out) {
    const int tid = threadIdx.x;
    const int lane = tid & 63;
    const int wid = tid >> 6;
    const int row0 = blockIdx.x * 64 + wid * 16;
    const int r = lane & 15;      // batch row within tile (B-side n index)
    const int g = lane >> 4;      // k-group

    // ---- x row slice: k = {8g..8g+7} and {32+8g..32+8g+7}
    const float* xp = x + (size_t)(row0 + r) * DIM + 8 * g;
    float xf[16];
    *(float4*)(xf)      = *(const float4*)(xp);
    *(float4*)(xf + 4)  = *(const float4*)(xp + 4);
    *(float4*)(xf + 8)  = *(const float4*)(xp + 32);
    *(float4*)(xf + 12) = *(const float4*)(xp + 36);

    // ---- norm (reduce over the 4 lanes sharing row r)
    float n0 = 0.f;
#pragma unroll
    for (int i = 0; i < 16; ++i) n0 = fmaf(xf[i], xf[i], n0);
    n0 += __shfl_xor(n0, 16);
    n0 += __shfl_xor(n0, 32);
    const float inv = 1.0f / n0;

    // ---- hi/lo bf16 x-fragments (chunk c: k = 32c + 8g .. +7)
    bf16x8 xh[2], xl[2];
    split8(xf,     xh[0], xl[0]);
    split8(xf + 8, xh[1], xl[1]);

    // ---- MFMA main loop: A = M fragment (global, L1-hot), B = x fragment
    const f32x4 z = {0.f, 0.f, 0.f, 0.f};
    f32x4 acr[4] = {z, z, z, z};
    f32x4 aci[4] = {z, z, z, z};
    const bf16x8* bb = (const bf16x8*)Bf + lane;   // frag f slice at bb[f*64]

#pragma unroll
    for (int jt = 0; jt < 4; ++jt) {
#pragma unroll
        for (int c = 0; c < 2; ++c) {
            const int f0 = (jt * 2 + c) * 4;
            bf16x8 mrh = bb[(f0 + 0) * 64];
            bf16x8 mrl = bb[(f0 + 1) * 64];
            bf16x8 mih = bb[(f0 + 2) * 64];
            bf16x8 mil = bb[(f0 + 3) * 64];
            acr[jt] = __builtin_amdgcn_mfma_f32_16x16x32_bf16(mrh, xh[c], acr[jt], 0, 0, 0);
            acr[jt] = __builtin_amdgcn_mfma_f32_16x16x32_bf16(mrh, xl[c], acr[jt], 0, 0, 0);
            acr[jt] = __builtin_amdgcn_mfma_f32_16x16x32_bf16(mrl, xh[c], acr[jt], 0, 0, 0);
            aci[jt] = __builtin_amdgcn_mfma_f32_16x16x32_bf16(mih, xh[c], aci[jt], 0, 0, 0);
            aci[jt] = __builtin_amdgcn_mfma_f32_16x16x32_bf16(mih, xl[c], aci[jt], 0, 0, 0);
            aci[jt] = __builtin_amdgcn_mfma_f32_16x16x32_bf16(mil, xh[c], aci[jt], 0, 0, 0);
        }
    }

    // ---- epilogue: lane holds out[row0+r][jt*16 + 4g + v], v=0..3
    float* op = out + (size_t)(row0 + r) * DIM + 4 * g;
#pragma unroll
    for (int jt = 0; jt < 4; ++jt) {
        float4 o;
        o.x = (acr[jt][0] * acr[jt][0] + aci[jt][0] * aci[jt][0]) * inv;
        o.y = (acr[jt][1] * acr[jt][1] + aci[jt][1] * aci[jt][1]) * inv;
        o.z = (acr[jt][2] * acr[jt][2] + aci[jt][2] * aci[jt][2]) * inv;
        o.w = (acr[jt][3] * acr[jt][3] + aci[jt][3] * aci[jt][3]) * inv;
        *(float4*)(op + jt * 16) = o;
    }
}

extern "C" void kernel_launch(void* const* d_in, const int* in_sizes, int n_in,
                              void* d_out, int out_size, void* d_ws, size_t ws_size,
                              hipStream_t stream) {
    const float* x = (const float*)d_in[0];
    const float* w = (const float*)d_in[1];
    float* out = (float*)d_out;
    unsigned short* Bf = (unsigned short*)d_ws;   // 32 KB fragment image
    int B = in_sizes[0] / DIM;

    hipLaunchKernelGGL(build_M, dim3(DIM), dim3(64), 0, stream, w, Bf);
    hipLaunchKernelGGL(qenc_main, dim3(B / 64), dim3(256), 0, stream, x, Bf, out);
}

// Round 8
// 22.275 us; speedup vs baseline: 1.1007x; 1.1007x over previous
//
#include <hip/hip_runtime.h>
#include <hip/hip_bf16.h>

#define NQ 6
#define DIM 64
#define NLAYERS 6

typedef __attribute__((ext_vector_type(8))) short bf16x8;
typedef __attribute__((ext_vector_type(4))) float f32x4;

// async global->LDS copy, 16B per lane, linear (dest = wave-uniform base + lane*16)
#define GLOAD_LDS16(gp, lp) \
    __builtin_amdgcn_global_load_lds((const __attribute__((address_space(1))) void*)(gp), \
                                     (__attribute__((address_space(3))) void*)(lp), 16, 0, 0)

// ---------------------------------------------------------------------------
// build_M: fused circuit matrix M = P*U5*...*P*U0*F (complex 64x64), emitted
// as MFMA fragments (bf16 hi/lo split), frag-linear:
//   frag f = (jt*2 + chunk)*4 + plane  (0=r_hi 1=r_lo 2=i_hi 3=i_lo)
//   ushort addr = f*512 + lane16*8 + e
//   lane16 = (j&15) + 16*((k>>3)&3), chunk = k>>5, e = k&7, jt = j>>4.
// Role-agnostic packing: both operands use the same (lanegrp,e)->k bijection,
// so the positional A/B pairing is consistent (validated R4/R6/R7 all pass).
// ---------------------------------------------------------------------------
__global__ __launch_bounds__(64) void build_M(const float* __restrict__ w,
                                              unsigned short* __restrict__ Bf) {
    const int k = blockIdx.x;    // column 0..63
    const int j = threadIdx.x;   // row/lane 0..63

    int t = (j * k) & 63;
    float sv, cv;
    sincospif((float)t / 32.0f, &sv, &cv);   // exp(i*pi*t/32)
    float vr = cv * 0.125f;
    float vi = sv * 0.125f;

    int m = j;
#pragma unroll
    for (int q = 0; q < NQ; ++q) {
        int cb = 5 - q;
        int tb = 5 - ((q + 1) % NQ);
        if ((m >> cb) & 1) m ^= (1 << tb);
    }
    const int dst4 = m << 2;

    for (int l = 0; l < NLAYERS; ++l) {
#pragma unroll
        for (int q = 0; q < NQ; ++q) {
            float th = w[l * NQ + q] * 0.5f;
            float c = cosf(th), s = sinf(th);
            int b = 5 - q;
            float pr = __shfl_xor(vr, 1 << b);
            float pi = __shfl_xor(vi, 1 << b);
            float sgn = ((j >> b) & 1) ? s : -s;
            vr = c * vr + sgn * pr;
            vi = c * vi + sgn * pi;
        }
        vr = __int_as_float(__builtin_amdgcn_ds_permute(dst4, __float_as_int(vr)));
        vi = __int_as_float(__builtin_amdgcn_ds_permute(dst4, __float_as_int(vi)));
    }

    const int jt = j >> 4;
    const int lane16 = (j & 15) + 16 * ((k >> 3) & 3);
    const int chunk = k >> 5;
    const int e = k & 7;
    const int base = ((jt * 2 + chunk) * 4) * 512 + lane16 * 8 + e;

    __hip_bfloat16 rh = __float2bfloat16(vr);
    __hip_bfloat16 rl = __float2bfloat16(vr - __bfloat162float(rh));
    __hip_bfloat16 ih = __float2bfloat16(vi);
    __hip_bfloat16 il = __float2bfloat16(vi - __bfloat162float(ih));
    Bf[base]        = *(unsigned short*)&rh;
    Bf[base + 512]  = *(unsigned short*)&rl;
    Bf[base + 1024] = *(unsigned short*)&ih;
    Bf[base + 1536] = *(unsigned short*)&il;
}

__device__ __forceinline__ void split8(const float* f, bf16x8& h, bf16x8& l) {
#pragma unroll
    for (int i = 0; i < 8; ++i) {
        __hip_bfloat16 hh = __float2bfloat16(f[i]);
        __hip_bfloat16 ll = __float2bfloat16(f[i] - __bfloat162float(hh));
        h[i] = *(short*)&hh;
        l[i] = *(short*)&ll;
    }
}

// ---------------------------------------------------------------------------
// qenc_main: R4 skeleton (16 rows/wave, 4 waves/block, grid 1024 -> 16
// waves/CU) with: M as A-operand from LDS (staged via async global_load_lds),
// x as B-operand in regs (prefetched before the stage), lane-resident inv,
// float4-store epilogue.
// ---------------------------------------------------------------------------
__global__ __launch_bounds__(256) void qenc_main(const float* __restrict__ x,
                                                 const unsigned short* __restrict__ Bf,
                                                 float* __restrict__ out) {
    __shared__ __align__(16) unsigned short sB[16384];   // 32 KB
    const int tid = threadIdx.x;
    const int lane = tid & 63;
    const int wid = tid >> 6;
    const int row0 = blockIdx.x * 64 + wid * 16;
    const int r = lane & 15;      // batch row within tile (B-side n index)
    const int g = lane >> 4;      // k-group

    // ---- issue x loads first (latency hides under stage + barrier)
    const float* xp = x + (size_t)(row0 + r) * DIM + 8 * g;
    float4 va = *(const float4*)(xp);
    float4 vb = *(const float4*)(xp + 4);
    float4 vc = *(const float4*)(xp + 32);
    float4 vd = *(const float4*)(xp + 36);

    // ---- async stage M fragments to LDS: 8 x 16B per thread, linear
    {
        const unsigned short* gp = Bf + (size_t)tid * 8;   // 16B per thread
        unsigned short* lp = sB + (size_t)tid * 8;
#pragma unroll
        for (int i = 0; i < 8; ++i)
            GLOAD_LDS16(gp + i * 2048, lp + i * 2048);     // 4096B chunks
    }

    float xf[16];
    *(float4*)(xf)      = va;  *(float4*)(xf + 4)  = vb;
    *(float4*)(xf + 8)  = vc;  *(float4*)(xf + 12) = vd;

    // ---- norm (reduce over the 4 lanes sharing row r)
    float n0 = 0.f;
#pragma unroll
    for (int i = 0; i < 16; ++i) n0 = fmaf(xf[i], xf[i], n0);
    n0 += __shfl_xor(n0, 16);
    n0 += __shfl_xor(n0, 32);
    const float inv = 1.0f / n0;

    // ---- hi/lo bf16 x-fragments (chunk c: k = 32c + 8g .. +7)
    bf16x8 xh[2], xl[2];
    split8(xf,     xh[0], xl[0]);
    split8(xf + 8, xh[1], xl[1]);

    __syncthreads();   // drains vmcnt(0): staged LDS ready

    // ---- MFMA main loop: A = M fragment (LDS), B = x fragment (regs)
    const f32x4 z = {0.f, 0.f, 0.f, 0.f};
    f32x4 acr[4] = {z, z, z, z};
    f32x4 aci[4] = {z, z, z, z};
    const unsigned short* bp = sB + lane * 8;

#pragma unroll
    for (int jt = 0; jt < 4; ++jt) {
#pragma unroll
        for (int c = 0; c < 2; ++c) {
            const unsigned short* fb = bp + ((jt * 2 + c) * 4) * 512;
            bf16x8 mrh = *(const bf16x8*)(fb);
            bf16x8 mrl = *(const bf16x8*)(fb + 512);
            bf16x8 mih = *(const bf16x8*)(fb + 1024);
            bf16x8 mil = *(const bf16x8*)(fb + 1536);
            acr[jt] = __builtin_amdgcn_mfma_f32_16x16x32_bf16(mrh, xh[c], acr[jt], 0, 0, 0);
            acr[jt] = __builtin_amdgcn_mfma_f32_16x16x32_bf16(mrh, xl[c], acr[jt], 0, 0, 0);
            acr[jt] = __builtin_amdgcn_mfma_f32_16x16x32_bf16(mrl, xh[c], acr[jt], 0, 0, 0);
            aci[jt] = __builtin_amdgcn_mfma_f32_16x16x32_bf16(mih, xh[c], aci[jt], 0, 0, 0);
            aci[jt] = __builtin_amdgcn_mfma_f32_16x16x32_bf16(mih, xl[c], aci[jt], 0, 0, 0);
            aci[jt] = __builtin_amdgcn_mfma_f32_16x16x32_bf16(mil, xh[c], aci[jt], 0, 0, 0);
        }
    }

    // ---- epilogue: lane holds out[row0+r][jt*16 + 4g + v], v=0..3
    float* op = out + (size_t)(row0 + r) * DIM + 4 * g;
#pragma unroll
    for (int jt = 0; jt < 4; ++jt) {
        float4 o;
        o.x = (acr[jt][0] * acr[jt][0] + aci[jt][0] * aci[jt][0]) * inv;
        o.y = (acr[jt][1] * acr[jt][1] + aci[jt][1] * aci[jt][1]) * inv;
        o.z = (acr[jt][2] * acr[jt][2] + aci[jt][2] * aci[jt][2]) * inv;
        o.w = (acr[jt][3] * acr[jt][3] + aci[jt][3] * aci[jt][3]) * inv;
        *(float4*)(op + jt * 16) = o;
    }
}

extern "C" void kernel_launch(void* const* d_in, const int* in_sizes, int n_in,
                              void* d_out, int out_size, void* d_ws, size_t ws_size,
                              hipStream_t stream) {
    const float* x = (const float*)d_in[0];
    const float* w = (const float*)d_in[1];
    float* out = (float*)d_out;
    unsigned short* Bf = (unsigned short*)d_ws;   // 32 KB fragment image
    int B = in_sizes[0] / DIM;

    hipLaunchKernelGGL(build_M, dim3(DIM), dim3(64), 0, stream, w, Bf);
    hipLaunchKernelGGL(qenc_main, dim3(B / 64), dim3(256), 0, stream, x, Bf, out);
}

// Round 9
// 17.348 us; speedup vs baseline: 1.4133x; 1.2840x over previous
//
#include <hip/hip_runtime.h>
#include <hip/hip_bf16.h>

#define NQ 6
#define DIM 64
#define NLAYERS 6

typedef __attribute__((ext_vector_type(8))) short bf16x8;
typedef __attribute__((ext_vector_type(4))) float f32x4;

// async global->LDS copy, 16B per lane, linear (dest = wave-uniform base + lane*16)
#define GLOAD_LDS16(gp, lp) \
    __builtin_amdgcn_global_load_lds((const __attribute__((address_space(1))) void*)(gp), \
                                     (__attribute__((address_space(3))) void*)(lp), 16, 0, 0)

// ---------------------------------------------------------------------------
// build_M: fused circuit matrix M = P*U5*...*P*U0*F (complex 64x64), emitted
// as MFMA fragments (bf16 hi/lo split), frag-linear:
//   frag f = (jt*2 + chunk)*4 + plane  (0=r_hi 1=r_lo 2=i_hi 3=i_lo)
//   ushort addr = f*512 + lane16*8 + e
//   lane16 = (j&15) + 16*((k>>3)&3), chunk = k>>5, e = k&7, jt = j>>4.
// Role-agnostic packing: both operands use the same (lanegrp,e)->k bijection.
// Trig via HW v_sin/v_cos (__sincosf): abs err ~1e-5, propagates to ~3.6e-4
// on M over 36 rotations -- within the 10x absmax margin.
// ---------------------------------------------------------------------------
__global__ __launch_bounds__(64) void build_M(const float* __restrict__ w,
                                              unsigned short* __restrict__ Bf) {
    const int k = blockIdx.x;    // column 0..63
    const int j = threadIdx.x;   // row/lane 0..63

    int t = (j * k) & 63;
    float sv, cv;
    __sincosf((float)t * (3.14159265358979f / 32.0f), &sv, &cv);  // exp(i*pi*t/32)
    float vr = cv * 0.125f;
    float vi = sv * 0.125f;

    int m = j;
#pragma unroll
    for (int q = 0; q < NQ; ++q) {
        int cb = 5 - q;
        int tb = 5 - ((q + 1) % NQ);
        if ((m >> cb) & 1) m ^= (1 << tb);
    }
    const int dst4 = m << 2;

#pragma unroll
    for (int l = 0; l < NLAYERS; ++l) {
#pragma unroll
        for (int q = 0; q < NQ; ++q) {
            float th = w[l * NQ + q] * 0.5f;
            float c = __cosf(th), s = __sinf(th);
            int b = 5 - q;
            float pr = __shfl_xor(vr, 1 << b);
            float pi = __shfl_xor(vi, 1 << b);
            float sgn = ((j >> b) & 1) ? s : -s;
            vr = c * vr + sgn * pr;
            vi = c * vi + sgn * pi;
        }
        vr = __int_as_float(__builtin_amdgcn_ds_permute(dst4, __float_as_int(vr)));
        vi = __int_as_float(__builtin_amdgcn_ds_permute(dst4, __float_as_int(vi)));
    }

    const int jt = j >> 4;
    const int lane16 = (j & 15) + 16 * ((k >> 3) & 3);
    const int chunk = k >> 5;
    const int e = k & 7;
    const int base = ((jt * 2 + chunk) * 4) * 512 + lane16 * 8 + e;

    __hip_bfloat16 rh = __float2bfloat16(vr);
    __hip_bfloat16 rl = __float2bfloat16(vr - __bfloat162float(rh));
    __hip_bfloat16 ih = __float2bfloat16(vi);
    __hip_bfloat16 il = __float2bfloat16(vi - __bfloat162float(ih));
    Bf[base]        = *(unsigned short*)&rh;
    Bf[base + 512]  = *(unsigned short*)&rl;
    Bf[base + 1024] = *(unsigned short*)&ih;
    Bf[base + 1536] = *(unsigned short*)&il;
}

__device__ __forceinline__ void split8(const float* f, bf16x8& h, bf16x8& l) {
#pragma unroll
    for (int i = 0; i < 8; ++i) {
        __hip_bfloat16 hh = __float2bfloat16(f[i]);
        __hip_bfloat16 ll = __float2bfloat16(f[i] - __bfloat162float(hh));
        h[i] = *(short*)&hh;
        l[i] = *(short*)&ll;
    }
}

// ---------------------------------------------------------------------------
// qenc_main: 512-thr blocks (8 waves), grid 512 -> 2 blocks/CU, 16 waves/CU
// (same TLP as R4, half the redundant 32KB stages). Per wave: 16 rows.
// M = A-operand from LDS (async global_load_lds stage), x = B-operand in
// regs (prefetched before stage). Lane-resident inv, float4 epilogue.
// ---------------------------------------------------------------------------
__global__ __launch_bounds__(512) void qenc_main(const float* __restrict__ x,
                                                 const unsigned short* __restrict__ Bf,
                                                 float* __restrict__ out) {
    __shared__ __align__(16) unsigned short sB[16384];   // 32 KB
    const int tid = threadIdx.x;
    const int lane = tid & 63;
    const int wid = tid >> 6;                 // 0..7
    const int row0 = blockIdx.x * 128 + wid * 16;
    const int r = lane & 15;      // batch row within tile (B-side n index)
    const int g = lane >> 4;      // k-group

    // ---- issue x loads first (latency hides under stage + barrier)
    const float* xp = x + (size_t)(row0 + r) * DIM + 8 * g;
    float4 va = *(const float4*)(xp);
    float4 vb = *(const float4*)(xp + 4);
    float4 vc = *(const float4*)(xp + 32);
    float4 vd = *(const float4*)(xp + 36);

    // ---- async stage M fragments to LDS: 4 x 16B per thread, linear
    {
        const unsigned short* gp = Bf + (size_t)tid * 8;   // 16B per thread
        unsigned short* lp = sB + (size_t)tid * 8;
#pragma unroll
        for (int i = 0; i < 4; ++i)
            GLOAD_LDS16(gp + i * 4096, lp + i * 4096);     // 8192B chunks
    }

    float xf[16];
    *(float4*)(xf)      = va;  *(float4*)(xf + 4)  = vb;
    *(float4*)(xf + 8)  = vc;  *(float4*)(xf + 12) = vd;

    // ---- norm (reduce over the 4 lanes sharing row r)
    float n0 = 0.f;
#pragma unroll
    for (int i = 0; i < 16; ++i) n0 = fmaf(xf[i], xf[i], n0);
    n0 += __shfl_xor(n0, 16);
    n0 += __shfl_xor(n0, 32);
    const float inv = 1.0f / n0;

    // ---- hi/lo bf16 x-fragments (chunk c: k = 32c + 8g .. +7)
    bf16x8 xh[2], xl[2];
    split8(xf,     xh[0], xl[0]);
    split8(xf + 8, xh[1], xl[1]);

    __syncthreads();   // drains vmcnt(0): staged LDS ready

    // ---- MFMA main loop: A = M fragment (LDS), B = x fragment (regs)
    const f32x4 z = {0.f, 0.f, 0.f, 0.f};
    f32x4 acr[4] = {z, z, z, z};
    f32x4 aci[4] = {z, z, z, z};
    const unsigned short* bp = sB + lane * 8;

#pragma unroll
    for (int jt = 0; jt < 4; ++jt) {
#pragma unroll
        for (int c = 0; c < 2; ++c) {
            const unsigned short* fb = bp + ((jt * 2 + c) * 4) * 512;
            bf16x8 mrh = *(const bf16x8*)(fb);
            bf16x8 mrl = *(const bf16x8*)(fb + 512);
            bf16x8 mih = *(const bf16x8*)(fb + 1024);
            bf16x8 mil = *(const bf16x8*)(fb + 1536);
            acr[jt] = __builtin_amdgcn_mfma_f32_16x16x32_bf16(mrh, xh[c], acr[jt], 0, 0, 0);
            acr[jt] = __builtin_amdgcn_mfma_f32_16x16x32_bf16(mrh, xl[c], acr[jt], 0, 0, 0);
            acr[jt] = __builtin_amdgcn_mfma_f32_16x16x32_bf16(mrl, xh[c], acr[jt], 0, 0, 0);
            aci[jt] = __builtin_amdgcn_mfma_f32_16x16x32_bf16(mih, xh[c], aci[jt], 0, 0, 0);
            aci[jt] = __builtin_amdgcn_mfma_f32_16x16x32_bf16(mih, xl[c], aci[jt], 0, 0, 0);
            aci[jt] = __builtin_amdgcn_mfma_f32_16x16x32_bf16(mil, xh[c], aci[jt], 0, 0, 0);
        }
    }

    // ---- epilogue: lane holds out[row0+r][jt*16 + 4g + v], v=0..3
    float* op = out + (size_t)(row0 + r) * DIM + 4 * g;
#pragma unroll
    for (int jt = 0; jt < 4; ++jt) {
        float4 o;
        o.x = (acr[jt][0] * acr[jt][0] + aci[jt][0] * aci[jt][0]) * inv;
        o.y = (acr[jt][1] * acr[jt][1] + aci[jt][1] * aci[jt][1]) * inv;
        o.z = (acr[jt][2] * acr[jt][2] + aci[jt][2] * aci[jt][2]) * inv;
        o.w = (acr[jt][3] * acr[jt][3] + aci[jt][3] * aci[jt][3]) * inv;
        *(float4*)(op + jt * 16) = o;
    }
}

extern "C" void kernel_launch(void* const* d_in, const int* in_sizes, int n_in,
                              void* d_out, int out_size, void* d_ws, size_t ws_size,
                              hipStream_t stream) {
    const float* x = (const float*)d_in[0];
    const float* w = (const float*)d_in[1];
    float* out = (float*)d_out;
    unsigned short* Bf = (unsigned short*)d_ws;   // 32 KB fragment image
    int B = in_sizes[0] / DIM;

    hipLaunchKernelGGL(build_M, dim3(DIM), dim3(64), 0, stream, w, Bf);
    hipLaunchKernelGGL(qenc_main, dim3(B / 128), dim3(512), 0, stream, x, Bf, out);
}